// Round 16
// baseline (35.926 us; speedup 1.0000x reference)
//
#include <hip/hip_runtime.h>

// ROUND 15b = ROUND 15 with the NT-load type fixed (ext_vector float2 instead of
// HIP_vector_type). Non-temporal dist path + triplet x4 BISECTION, unchanged design.

#define EPSF 1e-8f
#define MARGINF 0.5f
#define BN 512
#define DD 768
#define BT 64
#define GBLK 64
#define NBLK 32
#define CHK 128
#define NCHK 6
#define LP 136

typedef __attribute__((ext_vector_type(8))) short bf16x8;
typedef __attribute__((ext_vector_type(4))) float f32x4;
typedef __attribute__((ext_vector_type(2))) float f32x2;

__device__ __forceinline__ short f2bf(float f) {
    unsigned int u = __float_as_uint(f);
    return (short)((u + 0x7FFFu + ((u >> 16) & 1u)) >> 16);  // RNE
}

__device__ __forceinline__ bf16x8 pack8(const float4& a, const float4& b) {
    bf16x8 r;
    r[0] = f2bf(a.x); r[1] = f2bf(a.y); r[2] = f2bf(a.z); r[3] = f2bf(a.w);
    r[4] = f2bf(b.x); r[5] = f2bf(b.y); r[6] = f2bf(b.z); r[7] = f2bf(b.w);
    return r;
}

// ---------------- Node 1: full-K MFMA gram (blocks 0..63) + norms (64..95) ----------------
__global__ __launch_bounds__(1024) void prep_kernel(const float* __restrict__ x,
                                                    float* __restrict__ invn,
                                                    float* __restrict__ dist) {
    int b = blockIdx.x;
    int t = threadIdx.x;
    int wv = t >> 6, lane = t & 63;

    if (b >= GBLK) {
        int row = (b - GBLK) * 16 + wv;
        float s = 0.f;
#pragma unroll
        for (int c = 0; c < 3; ++c) {
            float4 v = *(const float4*)&x[row * DD + (lane + c * 64) * 4];
            s += v.x * v.x + v.y * v.y + v.z * v.z + v.w * v.w;
        }
        for (int off = 32; off; off >>= 1) s += __shfl_down(s, off, 64);
        if (lane == 0) invn[row] = 1.0f / fmaxf(sqrtf(s), EPSF);
        return;
    }

    __shared__ __align__(16) short As[BT][LP];
    __shared__ __align__(16) short Bs[BT][LP];
    int bi = b >> 3, bj = b & 7;
    int i0 = bi * BT, j0 = bj * BT;

    int wr = wv >> 2, wc = wv & 3;
    int r16 = lane & 15, kb8 = (lane >> 4) * 8;
    int srow = t >> 4, sf = (t & 15) * 8;

    const float* arow = &x[(i0 + srow) * DD + sf];
    const float* brow = &x[(j0 + srow) * DD + sf];

    f32x4 acc = (f32x4){0.f, 0.f, 0.f, 0.f};
    for (int c = 0; c < NCHK; ++c) {
        int kb = c * CHK;
        float4 a0 = *(const float4*)(arow + kb);
        float4 a1 = *(const float4*)(arow + kb + 4);
        float4 b0 = *(const float4*)(brow + kb);
        float4 b1 = *(const float4*)(brow + kb + 4);
        __syncthreads();
        *(bf16x8*)&As[srow][sf] = pack8(a0, a1);
        *(bf16x8*)&Bs[srow][sf] = pack8(b0, b1);
        __syncthreads();
#pragma unroll
        for (int s = 0; s < 4; ++s) {
            bf16x8 af = *(const bf16x8*)&As[wr * 16 + r16][kb8 + s * 32];
            bf16x8 bf_ = *(const bf16x8*)&Bs[wc * 16 + r16][kb8 + s * 32];
            acc = __builtin_amdgcn_mfma_f32_16x16x32_bf16(af, bf_, acc, 0, 0, 0);
        }
    }

    // NT stores: don't leave dist dirty in this XCD's L2 (read-once by triplet)
    int crow = i0 + wr * 16 + (lane >> 4) * 4;
    int ccol = j0 + wc * 16 + r16;
#pragma unroll
    for (int r = 0; r < 4; ++r)
        __builtin_nontemporal_store(acc[r], &dist[(crow + r) * BN + ccol]);
}

// ---------------- Node 2: triplet (NT dist read) ----------------
__global__ __launch_bounds__(256) void triplet_kernel(const float* __restrict__ dist,
                                                      const float* __restrict__ invn,
                                                      const int* __restrict__ labels,
                                                      float* __restrict__ psum,
                                                      unsigned int* __restrict__ pcnt) {
    int i = blockIdx.x;
    int t = threadIdx.x;
    int w = t >> 6, lane = t & 63;
    __shared__ float drow[BN];
    __shared__ int lab[BN];
    __shared__ __align__(16) float dpos[528];
    __shared__ int wcnt[8];
    __shared__ int woff[9];
    __shared__ float redf[4];
    __shared__ unsigned int redc[4];

    lab[t] = labels[t];
    lab[t + 256] = labels[t + 256];
    float inv_i = invn[i];
    {
        float2 iv = *(const float2*)&invn[2 * t];
        f32x2 p = __builtin_nontemporal_load((const f32x2*)&dist[i * BN + 2 * t]);
        drow[2 * t]     = 1.0f - p.x * inv_i * iv.x;
        drow[2 * t + 1] = 1.0f - p.y * inv_i * iv.y;
    }
    __syncthreads();

    int li = lab[i];
    bool p0 = (lab[t] == li) && (t != i);
    bool p1 = (lab[t + 256] == li) && ((t + 256) != i);
    unsigned long long m0 = __ballot(p0);
    unsigned long long m1 = __ballot(p1);
    if (lane == 0) { wcnt[w] = __popcll(m0); wcnt[4 + w] = __popcll(m1); }
    __syncthreads();
    if (t == 0) {
        int s = 0;
#pragma unroll
        for (int q = 0; q < 8; ++q) { woff[q] = s; s += wcnt[q]; }
        woff[8] = s;
    }
    __syncthreads();
    unsigned long long lmask = (1ull << lane) - 1ull;
    if (p0) dpos[woff[w] + __popcll(m0 & lmask)] = drow[t] + MARGINF;
    if (p1) dpos[woff[4 + w] + __popcll(m1 & lmask)] = drow[t + 256] + MARGINF;
    int npos = woff[8];
    int npad = (npos + 15) & ~15;
    if (t < npad - npos) dpos[npos + t] = -1e30f;
    __syncthreads();

    float dk0 = (lab[t] != li) ? drow[t] : 1e30f;
    float dk1 = (lab[t + 256] != li) ? drow[t + 256] : 1e30f;
    float sum = 0.f;
    unsigned int cnt = 0;
    for (int n = 0; n < npad; n += 16) {
        float4 q[4];
#pragma unroll
        for (int v = 0; v < 4; ++v) q[v] = *(const float4*)&dpos[n + v * 4];
#pragma unroll
        for (int v = 0; v < 4; ++v) {
            float bv[4] = {q[v].x, q[v].y, q[v].z, q[v].w};
#pragma unroll
            for (int u = 0; u < 4; ++u) {
                float v0 = bv[u] - dk0;
                float v1 = bv[u] - dk1;
                sum += fmaxf(v0, 0.f);
                if (v0 > EPSF) cnt++;
                sum += fmaxf(v1, 0.f);
                if (v1 > EPSF) cnt++;
            }
        }
    }
    for (int off = 32; off; off >>= 1) {
        sum += __shfl_down(sum, off, 64);
        cnt += __shfl_down(cnt, off, 64);
    }
    if (lane == 0) { redf[w] = sum; redc[w] = cnt; }
    __syncthreads();
    if (t == 0) {
        psum[i] = redf[0] + redf[1] + redf[2] + redf[3];
        pcnt[i] = redc[0] + redc[1] + redc[2] + redc[3];
    }
}

// ---------------- Node 3: final reduce ----------------
__global__ __launch_bounds__(256) void reduce_kernel(const float* __restrict__ psum,
                                                     const unsigned int* __restrict__ pcnt,
                                                     float* __restrict__ out) {
    int t = threadIdx.x;
    double s = (double)psum[t] + (double)psum[t + 256];
    double c = (double)pcnt[t] + (double)pcnt[t + 256];
    for (int off = 32; off; off >>= 1) {
        s += __shfl_down(s, off, 64);
        c += __shfl_down(c, off, 64);
    }
    __shared__ double sred[4], cred[4];
    if ((t & 63) == 0) { sred[t >> 6] = s; cred[t >> 6] = c; }
    __syncthreads();
    if (t == 0) {
        double stot = sred[0] + sred[1] + sred[2] + sred[3];
        double ctot = cred[0] + cred[1] + cred[2] + cred[3];
        out[0] = (float)(stot / (ctot + 1e-8));
    }
}

extern "C" void kernel_launch(void* const* d_in, const int* in_sizes, int n_in,
                              void* d_out, int out_size, void* d_ws, size_t ws_size,
                              hipStream_t stream) {
    const float* x = (const float*)d_in[0];
    const int* labels = (const int*)d_in[1];
    float* out = (float*)d_out;

    char* ws = (char*)d_ws;
    float* invn = (float*)(ws + 256);               // 2 KB
    float* psum = (float*)(ws + 4096);              // 2 KB
    unsigned int* pcnt = (unsigned int*)(ws + 8192);// 2 KB
    float* dist = (float*)(ws + 16384);             // 1 MB

    prep_kernel<<<GBLK + NBLK, 1024, 0, stream>>>(x, invn, dist);
    // BISECTION: triplet x4 (idempotent, identical outputs). T = (dur - rest)/4.
    triplet_kernel<<<BN, 256, 0, stream>>>(dist, invn, labels, psum, pcnt);
    triplet_kernel<<<BN, 256, 0, stream>>>(dist, invn, labels, psum, pcnt);
    triplet_kernel<<<BN, 256, 0, stream>>>(dist, invn, labels, psum, pcnt);
    triplet_kernel<<<BN, 256, 0, stream>>>(dist, invn, labels, psum, pcnt);
    reduce_kernel<<<1, 256, 0, stream>>>(psum, pcnt, out);
}

// Round 17
// 26.425 us; speedup vs baseline: 1.3595x; 1.3595x over previous
//
#include <hip/hip_runtime.h>

// ROUND 17: full-K prep at 4x parallelism (32x32 tiles, 256 gram blocks) + prep x2
// BISECTION (idempotent). Triplet/reduce byte-identical to R14. Decision table in journal.

#define EPSF 1e-8f
#define MARGINF 0.5f
#define BN 512
#define DD 768
#define GT 32      // gram tile 32x32
#define GBLK 256   // 16x16 tiles
#define NORMBLK 128
#define CHK 128
#define NCHK 6
#define LP 136     // shorts/row: 68 dwords % 32 = 4 -> 2-way max on stage writes (free)

typedef __attribute__((ext_vector_type(8))) short bf16x8;
typedef __attribute__((ext_vector_type(4))) float f32x4;

__device__ __forceinline__ short f2bf(float f) {
    unsigned int u = __float_as_uint(f);
    return (short)((u + 0x7FFFu + ((u >> 16) & 1u)) >> 16);  // RNE
}

__device__ __forceinline__ bf16x8 pack8(const float4& a, const float4& b) {
    bf16x8 r;
    r[0] = f2bf(a.x); r[1] = f2bf(a.y); r[2] = f2bf(a.z); r[3] = f2bf(a.w);
    r[4] = f2bf(b.x); r[5] = f2bf(b.y); r[6] = f2bf(b.z); r[7] = f2bf(b.w);
    return r;
}

// ---------------- Node 1: full-K MFMA gram, 32x32 tiles (blocks 0..255) + norms (256..383) ----------------
__global__ __launch_bounds__(256) void prep_kernel(const float* __restrict__ x,
                                                   float* __restrict__ invn,
                                                   float* __restrict__ dist) {
    int b = blockIdx.x;
    int t = threadIdx.x;
    int wv = t >> 6, lane = t & 63;

    if (b >= GBLK) {
        // ----- norm task: 128 blocks x 4 rows, one row per wave (R10 proven shape) -----
        int row = (b - GBLK) * 4 + wv;
        float s = 0.f;
#pragma unroll
        for (int c = 0; c < 3; ++c) {
            float4 v = *(const float4*)&x[row * DD + (lane + c * 64) * 4];
            s += v.x * v.x + v.y * v.y + v.z * v.z + v.w * v.w;
        }
        for (int off = 32; off; off >>= 1) s += __shfl_down(s, off, 64);
        if (lane == 0) invn[row] = 1.0f / fmaxf(sqrtf(s), EPSF);
        return;
    }

    __shared__ __align__(16) short As[GT][LP];   // 8.7 KB
    __shared__ __align__(16) short Bs[GT][LP];   // 17.4 KB total
    int bi = b >> 4, bj = b & 15;
    int i0 = bi * GT, j0 = bj * GT;

    int wr = wv >> 1, wc = wv & 1;         // wave's 16x16 fragment within 32x32 tile
    int r16 = lane & 15, kb8 = (lane >> 4) * 8;
    int srow = t >> 3, sf = (t & 7) * 16;  // staging: 8 threads/row x 16 floats

    const float* arow = &x[(i0 + srow) * DD + sf];
    const float* brow = &x[(j0 + srow) * DD + sf];

    f32x4 acc = (f32x4){0.f, 0.f, 0.f, 0.f};
    for (int c = 0; c < NCHK; ++c) {
        int kb = c * CHK;
        float4 a0 = *(const float4*)(arow + kb);
        float4 a1 = *(const float4*)(arow + kb + 4);
        float4 a2 = *(const float4*)(arow + kb + 8);
        float4 a3 = *(const float4*)(arow + kb + 12);
        float4 b0 = *(const float4*)(brow + kb);
        float4 b1 = *(const float4*)(brow + kb + 4);
        float4 b2 = *(const float4*)(brow + kb + 8);
        float4 b3 = *(const float4*)(brow + kb + 12);
        __syncthreads();   // previous chunk's fragment reads done
        *(bf16x8*)&As[srow][sf]     = pack8(a0, a1);
        *(bf16x8*)&As[srow][sf + 8] = pack8(a2, a3);
        *(bf16x8*)&Bs[srow][sf]     = pack8(b0, b1);
        *(bf16x8*)&Bs[srow][sf + 8] = pack8(b2, b3);
        __syncthreads();
#pragma unroll
        for (int s = 0; s < 4; ++s) {
            bf16x8 af = *(const bf16x8*)&As[wr * 16 + r16][kb8 + s * 32];
            bf16x8 bf_ = *(const bf16x8*)&Bs[wc * 16 + r16][kb8 + s * 32];
            acc = __builtin_amdgcn_mfma_f32_16x16x32_bf16(af, bf_, acc, 0, 0, 0);
        }
    }

    // C/D layout: col = lane&15, row = (lane>>4)*4 + reg   [verified R6-R16]
    int crow = i0 + wr * 16 + (lane >> 4) * 4;
    int ccol = j0 + wc * 16 + r16;
#pragma unroll
    for (int r = 0; r < 4; ++r)
        dist[(crow + r) * BN + ccol] = acc[r];
}

// ---------------- Node 2: triplet (byte-identical to R14) ----------------
__global__ __launch_bounds__(256) void triplet_kernel(const float* __restrict__ dist,
                                                      const float* __restrict__ invn,
                                                      const int* __restrict__ labels,
                                                      float* __restrict__ psum,
                                                      unsigned int* __restrict__ pcnt) {
    int i = blockIdx.x;
    int t = threadIdx.x;
    int w = t >> 6, lane = t & 63;
    __shared__ float drow[BN];
    __shared__ int lab[BN];
    __shared__ __align__(16) float dpos[528];
    __shared__ int wcnt[8];
    __shared__ int woff[9];
    __shared__ float redf[4];
    __shared__ unsigned int redc[4];

    lab[t] = labels[t];
    lab[t + 256] = labels[t + 256];
    float inv_i = invn[i];
    {
        float2 iv = *(const float2*)&invn[2 * t];
        float2 p = *(const float2*)&dist[i * BN + 2 * t];
        drow[2 * t]     = 1.0f - p.x * inv_i * iv.x;
        drow[2 * t + 1] = 1.0f - p.y * inv_i * iv.y;
    }
    __syncthreads();

    int li = lab[i];
    bool p0 = (lab[t] == li) && (t != i);
    bool p1 = (lab[t + 256] == li) && ((t + 256) != i);
    unsigned long long m0 = __ballot(p0);
    unsigned long long m1 = __ballot(p1);
    if (lane == 0) { wcnt[w] = __popcll(m0); wcnt[4 + w] = __popcll(m1); }
    __syncthreads();
    if (t == 0) {
        int s = 0;
#pragma unroll
        for (int q = 0; q < 8; ++q) { woff[q] = s; s += wcnt[q]; }
        woff[8] = s;
    }
    __syncthreads();
    unsigned long long lmask = (1ull << lane) - 1ull;
    if (p0) dpos[woff[w] + __popcll(m0 & lmask)] = drow[t] + MARGINF;
    if (p1) dpos[woff[4 + w] + __popcll(m1 & lmask)] = drow[t + 256] + MARGINF;
    int npos = woff[8];
    int npad = (npos + 15) & ~15;
    if (t < npad - npos) dpos[npos + t] = -1e30f;
    __syncthreads();

    float dk0 = (lab[t] != li) ? drow[t] : 1e30f;
    float dk1 = (lab[t + 256] != li) ? drow[t + 256] : 1e30f;
    float sum = 0.f;
    unsigned int cnt = 0;
    for (int n = 0; n < npad; n += 16) {
        float4 q[4];
#pragma unroll
        for (int v = 0; v < 4; ++v) q[v] = *(const float4*)&dpos[n + v * 4];
#pragma unroll
        for (int v = 0; v < 4; ++v) {
            float bv[4] = {q[v].x, q[v].y, q[v].z, q[v].w};
#pragma unroll
            for (int u = 0; u < 4; ++u) {
                float v0 = bv[u] - dk0;
                float v1 = bv[u] - dk1;
                sum += fmaxf(v0, 0.f);
                if (v0 > EPSF) cnt++;
                sum += fmaxf(v1, 0.f);
                if (v1 > EPSF) cnt++;
            }
        }
    }
    for (int off = 32; off; off >>= 1) {
        sum += __shfl_down(sum, off, 64);
        cnt += __shfl_down(cnt, off, 64);
    }
    if (lane == 0) { redf[w] = sum; redc[w] = cnt; }
    __syncthreads();
    if (t == 0) {
        psum[i] = redf[0] + redf[1] + redf[2] + redf[3];
        pcnt[i] = redc[0] + redc[1] + redc[2] + redc[3];
    }
}

// ---------------- Node 3: final reduce ----------------
__global__ __launch_bounds__(256) void reduce_kernel(const float* __restrict__ psum,
                                                     const unsigned int* __restrict__ pcnt,
                                                     float* __restrict__ out) {
    int t = threadIdx.x;
    double s = (double)psum[t] + (double)psum[t + 256];
    double c = (double)pcnt[t] + (double)pcnt[t + 256];
    for (int off = 32; off; off >>= 1) {
        s += __shfl_down(s, off, 64);
        c += __shfl_down(c, off, 64);
    }
    __shared__ double sred[4], cred[4];
    if ((t & 63) == 0) { sred[t >> 6] = s; cred[t >> 6] = c; }
    __syncthreads();
    if (t == 0) {
        double stot = sred[0] + sred[1] + sred[2] + sred[3];
        double ctot = cred[0] + cred[1] + cred[2] + cred[3];
        out[0] = (float)(stot / (ctot + 1e-8));
    }
}

extern "C" void kernel_launch(void* const* d_in, const int* in_sizes, int n_in,
                              void* d_out, int out_size, void* d_ws, size_t ws_size,
                              hipStream_t stream) {
    const float* x = (const float*)d_in[0];
    const int* labels = (const int*)d_in[1];
    float* out = (float*)d_out;

    char* ws = (char*)d_ws;
    float* invn = (float*)(ws + 256);               // 2 KB
    float* psum = (float*)(ws + 4096);              // 2 KB
    unsigned int* pcnt = (unsigned int*)(ws + 8192);// 2 KB
    float* dist = (float*)(ws + 16384);             // 1 MB

    // BISECTION: prep x2 (idempotent). P = contribution of one prep.
    prep_kernel<<<GBLK + NORMBLK, 256, 0, stream>>>(x, invn, dist);
    prep_kernel<<<GBLK + NORMBLK, 256, 0, stream>>>(x, invn, dist);
    triplet_kernel<<<BN, 256, 0, stream>>>(dist, invn, labels, psum, pcnt);
    reduce_kernel<<<1, 256, 0, stream>>>(psum, pcnt, out);
}

// Round 18
// 18.910 us; speedup vs baseline: 1.8998x; 1.3974x over previous
//
#include <hip/hip_runtime.h>

// ROUND 18 = ROUND 12 (19.42 us baseline) with ONE change: dotp stores are
// system-scope (write-through, no dirty L2 lines) to kill the ~8.8 us
// cross-kernel dirty-RAW wall that triplet pays reading dotp.

#define EPSF 1e-8f
#define MARGINF 0.5f
#define BN 512
#define DD 768
#define BT 64
#define SPLITK 8
#define KC (DD / SPLITK)  // 96
#define LPAD 104          // shorts per LDS row: 52 dwords, 52%32=20 -> <=2-way on frag reads
#define NORMBLK 128

typedef __attribute__((ext_vector_type(8))) short bf16x8;
typedef __attribute__((ext_vector_type(4))) float f32x4;

__device__ __forceinline__ short f2bf(float f) {
    unsigned int u = __float_as_uint(f);
    return (short)((u + 0x7FFFu + ((u >> 16) & 1u)) >> 16);  // RNE
}

__device__ __forceinline__ bf16x8 pack8(const float4& a, const float4& b) {
    bf16x8 r;
    r[0] = f2bf(a.x); r[1] = f2bf(a.y); r[2] = f2bf(a.z); r[3] = f2bf(a.w);
    r[4] = f2bf(b.x); r[5] = f2bf(b.y); r[6] = f2bf(b.z); r[7] = f2bf(b.w);
    return r;
}

// ---------------- Node 1: MFMA gram partials (blocks 0..511) + norms (512..639) ----------------
__global__ __launch_bounds__(256) void prep_kernel(const float* __restrict__ x,
                                                   float* __restrict__ invn,
                                                   float* __restrict__ dotp) {
    int b = blockIdx.x;
    int t = threadIdx.x;
    int wv = t >> 6, lane = t & 63;

    if (b >= BN) {
        int row = (b - BN) * 4 + wv;
        float s = 0.f;
#pragma unroll
        for (int c = 0; c < 3; ++c) {
            float4 v = *(const float4*)&x[row * DD + (lane + c * 64) * 4];
            s += v.x * v.x + v.y * v.y + v.z * v.z + v.w * v.w;
        }
        for (int off = 32; off; off >>= 1) s += __shfl_down(s, off, 64);
        if (lane == 0) invn[row] = 1.0f / fmaxf(sqrtf(s), EPSF);
        return;
    }

    __shared__ __align__(16) short As[BT][LPAD];
    __shared__ __align__(16) short Bs[BT][LPAD];
    int bz = b >> 6, bi = (b >> 3) & 7, bj = b & 7;
    int i0 = bi * BT, j0 = bj * BT, kbase = bz * KC;

    {
        int row = t >> 2, fq = t & 3;
        const float* ap = &x[(i0 + row) * DD + kbase + fq * 8];
        const float* bp = &x[(j0 + row) * DD + kbase + fq * 8];
#pragma unroll
        for (int cc = 0; cc < 3; ++cc) {
            float4 a0 = *(const float4*)(ap + cc * 32);
            float4 a1 = *(const float4*)(ap + cc * 32 + 4);
            float4 b0 = *(const float4*)(bp + cc * 32);
            float4 b1 = *(const float4*)(bp + cc * 32 + 4);
            *(bf16x8*)&As[row][fq * 8 + cc * 32] = pack8(a0, a1);
            *(bf16x8*)&Bs[row][fq * 8 + cc * 32] = pack8(b0, b1);
        }
    }
    __syncthreads();

    int r16 = lane & 15;
    int kb8 = (lane >> 4) * 8;

    f32x4 accf[4];
#pragma unroll
    for (int c = 0; c < 4; ++c) accf[c] = (f32x4){0.f, 0.f, 0.f, 0.f};

#pragma unroll
    for (int s = 0; s < 3; ++s) {
        bf16x8 af = *(const bf16x8*)&As[wv * 16 + r16][kb8 + s * 32];
#pragma unroll
        for (int c = 0; c < 4; ++c) {
            bf16x8 bf_ = *(const bf16x8*)&Bs[c * 16 + r16][kb8 + s * 32];
            accf[c] = __builtin_amdgcn_mfma_f32_16x16x32_bf16(af, bf_, accf[c], 0, 0, 0);
        }
    }

    // C/D layout: col = lane&15, row = (lane>>4)*4 + reg   [verified R6-R17]
    // SYSTEM-SCOPE stores: write-through, leave no dirty lines in this XCD's L2.
    float* o = dotp + (size_t)bz * BN * BN;
    int crow = i0 + wv * 16 + (lane >> 4) * 4;
#pragma unroll
    for (int c = 0; c < 4; ++c) {
        int ccol = j0 + c * 16 + r16;
#pragma unroll
        for (int r = 0; r < 4; ++r)
            __hip_atomic_store((unsigned int*)&o[(crow + r) * BN + ccol],
                               __float_as_uint(accf[c][r]),
                               __ATOMIC_RELAXED, __HIP_MEMORY_SCOPE_SYSTEM);
    }
}

// ---------------- Node 2: triplet — byte-identical to R12 ----------------
__global__ __launch_bounds__(256) void triplet_kernel(const float* __restrict__ dotp,
                                                      const float* __restrict__ invn,
                                                      const int* __restrict__ labels,
                                                      float* __restrict__ psum,
                                                      unsigned int* __restrict__ pcnt) {
    int i = blockIdx.x;
    int t = threadIdx.x;
    int w = t >> 6, lane = t & 63;
    __shared__ float drow[BN];
    __shared__ int lab[BN];
    __shared__ __align__(16) float dpos[528];
    __shared__ int wcnt[8];
    __shared__ int woff[9];
    __shared__ float redf[4];
    __shared__ unsigned int redc[4];

    lab[t] = labels[t];
    lab[t + 256] = labels[t + 256];
    float inv_i = invn[i];
#pragma unroll
    for (int e0 = 0; e0 < BN; e0 += 256) {
        int e = e0 + t;
        float s = 0.f;
#pragma unroll
        for (int z = 0; z < SPLITK; ++z) s += dotp[(size_t)z * BN * BN + i * BN + e];
        drow[e] = 1.0f - s * inv_i * invn[e];
    }
    __syncthreads();

    int li = lab[i];
    bool p0 = (lab[t] == li) && (t != i);
    bool p1 = (lab[t + 256] == li) && ((t + 256) != i);
    unsigned long long m0 = __ballot(p0);
    unsigned long long m1 = __ballot(p1);
    if (lane == 0) { wcnt[w] = __popcll(m0); wcnt[4 + w] = __popcll(m1); }
    __syncthreads();
    if (t == 0) {
        int s = 0;
#pragma unroll
        for (int q = 0; q < 8; ++q) { woff[q] = s; s += wcnt[q]; }
        woff[8] = s;
    }
    __syncthreads();
    unsigned long long lmask = (1ull << lane) - 1ull;
    if (p0) dpos[woff[w] + __popcll(m0 & lmask)] = drow[t] + MARGINF;
    if (p1) dpos[woff[4 + w] + __popcll(m1 & lmask)] = drow[t + 256] + MARGINF;
    int npos = woff[8];
    int npad = (npos + 15) & ~15;
    if (t < npad - npos) dpos[npos + t] = -1e30f;
    __syncthreads();

    float dk0 = (lab[t] != li) ? drow[t] : 1e30f;
    float dk1 = (lab[t + 256] != li) ? drow[t + 256] : 1e30f;
    float sum = 0.f;
    unsigned int cnt = 0;
    for (int n = 0; n < npad; n += 16) {
        float4 q[4];
#pragma unroll
        for (int v = 0; v < 4; ++v) q[v] = *(const float4*)&dpos[n + v * 4];
#pragma unroll
        for (int v = 0; v < 4; ++v) {
            float bv[4] = {q[v].x, q[v].y, q[v].z, q[v].w};
#pragma unroll
            for (int u = 0; u < 4; ++u) {
                float v0 = bv[u] - dk0;
                float v1 = bv[u] - dk1;
                sum += fmaxf(v0, 0.f);
                if (v0 > EPSF) cnt++;
                sum += fmaxf(v1, 0.f);
                if (v1 > EPSF) cnt++;
            }
        }
    }
    for (int off = 32; off; off >>= 1) {
        sum += __shfl_down(sum, off, 64);
        cnt += __shfl_down(cnt, off, 64);
    }
    if (lane == 0) { redf[w] = sum; redc[w] = cnt; }
    __syncthreads();
    if (t == 0) {
        psum[i] = redf[0] + redf[1] + redf[2] + redf[3];
        pcnt[i] = redc[0] + redc[1] + redc[2] + redc[3];
    }
}

// ---------------- Node 3: final reduce (1 block, deterministic) ----------------
__global__ __launch_bounds__(256) void reduce_kernel(const float* __restrict__ psum,
                                                     const unsigned int* __restrict__ pcnt,
                                                     float* __restrict__ out) {
    int t = threadIdx.x;
    double s = (double)psum[t] + (double)psum[t + 256];
    double c = (double)pcnt[t] + (double)pcnt[t + 256];
    for (int off = 32; off; off >>= 1) {
        s += __shfl_down(s, off, 64);
        c += __shfl_down(c, off, 64);
    }
    __shared__ double sred[4], cred[4];
    if ((t & 63) == 0) { sred[t >> 6] = s; cred[t >> 6] = c; }
    __syncthreads();
    if (t == 0) {
        double stot = sred[0] + sred[1] + sred[2] + sred[3];
        double ctot = cred[0] + cred[1] + cred[2] + cred[3];
        out[0] = (float)(stot / (ctot + 1e-8));
    }
}

extern "C" void kernel_launch(void* const* d_in, const int* in_sizes, int n_in,
                              void* d_out, int out_size, void* d_ws, size_t ws_size,
                              hipStream_t stream) {
    const float* x = (const float*)d_in[0];
    const int* labels = (const int*)d_in[1];
    float* out = (float*)d_out;

    char* ws = (char*)d_ws;
    float* invn = (float*)(ws + 256);               // 2 KB
    float* psum = (float*)(ws + 4096);              // 2 KB
    unsigned int* pcnt = (unsigned int*)(ws + 8192);// 2 KB
    float* dotp = (float*)(ws + 16384);             // 8 MB

    prep_kernel<<<BN + NORMBLK, 256, 0, stream>>>(x, invn, dotp);
    triplet_kernel<<<BN, 256, 0, stream>>>(dotp, invn, labels, psum, pcnt);
    reduce_kernel<<<1, 256, 0, stream>>>(psum, pcnt, out);
}

// Round 19
// 17.440 us; speedup vs baseline: 2.0599x; 1.0843x over previous
//
#include <hip/hip_runtime.h>

// ROUND 19 = R12 structure + XCD-MATCHED producer/consumer mapping:
// prep decode bi = b&7  -> all writers of anchor-row-group g are on XCD g (blockIdx%8==g);
// triplet block r -> anchor i = (r&7)*64 + (r>>3) -> reader runs on XCD g too.
// Dirty dotp lines become LOCAL-L2 hits instead of cross-XCD probes. Plain stores.

#define EPSF 1e-8f
#define MARGINF 0.5f
#define BN 512
#define DD 768
#define BT 64
#define SPLITK 8
#define KC (DD / SPLITK)  // 96
#define LPAD 104          // shorts per LDS row: 52 dwords, 52%32=20 -> <=2-way on frag reads
#define NORMBLK 128

typedef __attribute__((ext_vector_type(8))) short bf16x8;
typedef __attribute__((ext_vector_type(4))) float f32x4;

__device__ __forceinline__ short f2bf(float f) {
    unsigned int u = __float_as_uint(f);
    return (short)((u + 0x7FFFu + ((u >> 16) & 1u)) >> 16);  // RNE
}

__device__ __forceinline__ bf16x8 pack8(const float4& a, const float4& b) {
    bf16x8 r;
    r[0] = f2bf(a.x); r[1] = f2bf(a.y); r[2] = f2bf(a.z); r[3] = f2bf(a.w);
    r[4] = f2bf(b.x); r[5] = f2bf(b.y); r[6] = f2bf(b.z); r[7] = f2bf(b.w);
    return r;
}

// ---------------- Node 1: MFMA gram partials (blocks 0..511) + norms (512..639) ----------------
__global__ __launch_bounds__(256) void prep_kernel(const float* __restrict__ x,
                                                   float* __restrict__ invn,
                                                   float* __restrict__ dotp) {
    int b = blockIdx.x;
    int t = threadIdx.x;
    int wv = t >> 6, lane = t & 63;

    if (b >= BN) {
        int row = (b - BN) * 4 + wv;
        float s = 0.f;
#pragma unroll
        for (int c = 0; c < 3; ++c) {
            float4 v = *(const float4*)&x[row * DD + (lane + c * 64) * 4];
            s += v.x * v.x + v.y * v.y + v.z * v.z + v.w * v.w;
        }
        for (int off = 32; off; off >>= 1) s += __shfl_down(s, off, 64);
        if (lane == 0) invn[row] = 1.0f / fmaxf(sqrtf(s), EPSF);
        return;
    }

    __shared__ __align__(16) short As[BT][LPAD];
    __shared__ __align__(16) short Bs[BT][LPAD];
    // XCD-matched decode: row-group bi == b % 8 == this block's XCD
    int bi = b & 7, bj = (b >> 3) & 7, bz = b >> 6;
    int i0 = bi * BT, j0 = bj * BT, kbase = bz * KC;

    {
        int row = t >> 2, fq = t & 3;
        const float* ap = &x[(i0 + row) * DD + kbase + fq * 8];
        const float* bp = &x[(j0 + row) * DD + kbase + fq * 8];
#pragma unroll
        for (int cc = 0; cc < 3; ++cc) {
            float4 a0 = *(const float4*)(ap + cc * 32);
            float4 a1 = *(const float4*)(ap + cc * 32 + 4);
            float4 b0 = *(const float4*)(bp + cc * 32);
            float4 b1 = *(const float4*)(bp + cc * 32 + 4);
            *(bf16x8*)&As[row][fq * 8 + cc * 32] = pack8(a0, a1);
            *(bf16x8*)&Bs[row][fq * 8 + cc * 32] = pack8(b0, b1);
        }
    }
    __syncthreads();

    int r16 = lane & 15;
    int kb8 = (lane >> 4) * 8;

    f32x4 accf[4];
#pragma unroll
    for (int c = 0; c < 4; ++c) accf[c] = (f32x4){0.f, 0.f, 0.f, 0.f};

#pragma unroll
    for (int s = 0; s < 3; ++s) {
        bf16x8 af = *(const bf16x8*)&As[wv * 16 + r16][kb8 + s * 32];
#pragma unroll
        for (int c = 0; c < 4; ++c) {
            bf16x8 bf_ = *(const bf16x8*)&Bs[c * 16 + r16][kb8 + s * 32];
            accf[c] = __builtin_amdgcn_mfma_f32_16x16x32_bf16(af, bf_, accf[c], 0, 0, 0);
        }
    }

    // C/D layout: col = lane&15, row = (lane>>4)*4 + reg   [verified R6-R18]
    float* o = dotp + (size_t)bz * BN * BN;
    int crow = i0 + wv * 16 + (lane >> 4) * 4;
#pragma unroll
    for (int c = 0; c < 4; ++c) {
        int ccol = j0 + c * 16 + r16;
#pragma unroll
        for (int r = 0; r < 4; ++r)
            o[(crow + r) * BN + ccol] = accf[c][r];
    }
}

// ---------------- Node 2: triplet — XCD-matched anchor swizzle ----------------
__global__ __launch_bounds__(256) void triplet_kernel(const float* __restrict__ dotp,
                                                      const float* __restrict__ invn,
                                                      const int* __restrict__ labels,
                                                      float* __restrict__ psum,
                                                      unsigned int* __restrict__ pcnt) {
    int r_ = blockIdx.x;
    int i = ((r_ & 7) << 6) | (r_ >> 3);   // anchor: this block's XCD == writers' XCD
    int t = threadIdx.x;
    int w = t >> 6, lane = t & 63;
    __shared__ float drow[BN];
    __shared__ int lab[BN];
    __shared__ __align__(16) float dpos[528];
    __shared__ int wcnt[8];
    __shared__ int woff[9];
    __shared__ float redf[4];
    __shared__ unsigned int redc[4];

    lab[t] = labels[t];
    lab[t + 256] = labels[t + 256];
    float inv_i = invn[i];
#pragma unroll
    for (int e0 = 0; e0 < BN; e0 += 256) {
        int e = e0 + t;
        float s = 0.f;
#pragma unroll
        for (int z = 0; z < SPLITK; ++z) s += dotp[(size_t)z * BN * BN + i * BN + e];
        drow[e] = 1.0f - s * inv_i * invn[e];
    }
    __syncthreads();

    int li = lab[i];
    bool p0 = (lab[t] == li) && (t != i);
    bool p1 = (lab[t + 256] == li) && ((t + 256) != i);
    unsigned long long m0 = __ballot(p0);
    unsigned long long m1 = __ballot(p1);
    if (lane == 0) { wcnt[w] = __popcll(m0); wcnt[4 + w] = __popcll(m1); }
    __syncthreads();
    if (t == 0) {
        int s = 0;
#pragma unroll
        for (int q = 0; q < 8; ++q) { woff[q] = s; s += wcnt[q]; }
        woff[8] = s;
    }
    __syncthreads();
    unsigned long long lmask = (1ull << lane) - 1ull;
    if (p0) dpos[woff[w] + __popcll(m0 & lmask)] = drow[t] + MARGINF;
    if (p1) dpos[woff[4 + w] + __popcll(m1 & lmask)] = drow[t + 256] + MARGINF;
    int npos = woff[8];
    int npad = (npos + 15) & ~15;
    if (t < npad - npos) dpos[npos + t] = -1e30f;
    __syncthreads();

    float dk0 = (lab[t] != li) ? drow[t] : 1e30f;
    float dk1 = (lab[t + 256] != li) ? drow[t + 256] : 1e30f;
    float sum = 0.f;
    unsigned int cnt = 0;
    for (int n = 0; n < npad; n += 16) {
        float4 q[4];
#pragma unroll
        for (int v = 0; v < 4; ++v) q[v] = *(const float4*)&dpos[n + v * 4];
#pragma unroll
        for (int v = 0; v < 4; ++v) {
            float bv[4] = {q[v].x, q[v].y, q[v].z, q[v].w};
#pragma unroll
            for (int u = 0; u < 4; ++u) {
                float v0 = bv[u] - dk0;
                float v1 = bv[u] - dk1;
                sum += fmaxf(v0, 0.f);
                if (v0 > EPSF) cnt++;
                sum += fmaxf(v1, 0.f);
                if (v1 > EPSF) cnt++;
            }
        }
    }
    for (int off = 32; off; off >>= 1) {
        sum += __shfl_down(sum, off, 64);
        cnt += __shfl_down(cnt, off, 64);
    }
    if (lane == 0) { redf[w] = sum; redc[w] = cnt; }
    __syncthreads();
    if (t == 0) {
        psum[i] = redf[0] + redf[1] + redf[2] + redf[3];
        pcnt[i] = redc[0] + redc[1] + redc[2] + redc[3];
    }
}

// ---------------- Node 3: final reduce (1 block, deterministic) ----------------
__global__ __launch_bounds__(256) void reduce_kernel(const float* __restrict__ psum,
                                                     const unsigned int* __restrict__ pcnt,
                                                     float* __restrict__ out) {
    int t = threadIdx.x;
    double s = (double)psum[t] + (double)psum[t + 256];
    double c = (double)pcnt[t] + (double)pcnt[t + 256];
    for (int off = 32; off; off >>= 1) {
        s += __shfl_down(s, off, 64);
        c += __shfl_down(c, off, 64);
    }
    __shared__ double sred[4], cred[4];
    if ((t & 63) == 0) { sred[t >> 6] = s; cred[t >> 6] = c; }
    __syncthreads();
    if (t == 0) {
        double stot = sred[0] + sred[1] + sred[2] + sred[3];
        double ctot = cred[0] + cred[1] + cred[2] + cred[3];
        out[0] = (float)(stot / (ctot + 1e-8));
    }
}

extern "C" void kernel_launch(void* const* d_in, const int* in_sizes, int n_in,
                              void* d_out, int out_size, void* d_ws, size_t ws_size,
                              hipStream_t stream) {
    const float* x = (const float*)d_in[0];
    const int* labels = (const int*)d_in[1];
    float* out = (float*)d_out;

    char* ws = (char*)d_ws;
    float* invn = (float*)(ws + 256);               // 2 KB
    float* psum = (float*)(ws + 4096);              // 2 KB
    unsigned int* pcnt = (unsigned int*)(ws + 8192);// 2 KB
    float* dotp = (float*)(ws + 16384);             // 8 MB

    prep_kernel<<<BN + NORMBLK, 256, 0, stream>>>(x, invn, dotp);
    triplet_kernel<<<BN, 256, 0, stream>>>(dotp, invn, labels, psum, pcnt);
    reduce_kernel<<<1, 256, 0, stream>>>(psum, pcnt, out);
}